// Round 1
// baseline (6124.680 us; speedup 1.0000x reference)
//
#include <hip/hip_runtime.h>
#include <math.h>

#define LOG2PI 1.8378770664093453f

// Problem dims
constexpr int Bb = 16, Nn = 512, Tt = 16;
constexpr int dL = 128, dM = 256, dE = 32, Kt = 18;
constexpr int P = Bb * Nn;          // 8192 particles
constexpr int DIN = 416;            // dM + dL + dE

__device__ __forceinline__ float siluf(float x) { return x / (1.f + expf(-x)); }
__device__ __forceinline__ float softplusf(float x) {
    return (x > 20.f) ? x : log1pf(expf(x));
}

// ---------------------------------------------------------------------------
// k1: build input X = [h_exp | z | remb]  (P x 416). One wave per particle.
// ---------------------------------------------------------------------------
__global__ __launch_bounds__(256) void k1_build_inp(
    const float* __restrict__ rl, const float* __restrict__ z,
    const float* __restrict__ h_t, const float* __restrict__ pe_emb,
    float* __restrict__ X)
{
    int wave = threadIdx.x >> 6, lane = threadIdx.x & 63;
    int p = blockIdx.x * 4 + wave;
    int b = p >> 9;
    // softmax over all 18 regime logits (redundant per lane; L1 broadcast)
    float v[Kt];
    float m = -1e30f;
    #pragma unroll
    for (int k = 0; k < Kt; k++) { v[k] = rl[p * Kt + k]; m = fmaxf(m, v[k]); }
    float denom = 0.f;
    #pragma unroll
    for (int k = 0; k < Kt; k++) denom += expf(v[k] - m);
    float remb = 0.f;
    if (lane < dE) {
        #pragma unroll
        for (int k = 0; k < 8; k++)
            remb += (expf(v[k] - m) / denom) * pe_emb[k * dE + lane];
    }
    const float* hb = h_t + b * dM;
    float* Xr = X + (size_t)p * DIN;
    Xr[lane]       = hb[lane];
    Xr[64 + lane]  = hb[64 + lane];
    Xr[128 + lane] = hb[128 + lane];
    Xr[192 + lane] = hb[192 + lane];
    Xr[256 + lane] = z[p * dL + lane];
    Xr[320 + lane] = z[p * dL + 64 + lane];
    if (lane < dE) Xr[384 + lane] = remb;
}

// ---------------------------------------------------------------------------
// Tiled fp32 GEMM: C[M x NOUT] = act(A[M x K] @ W[K x NOUT] + bias)
// BM=BN=64, BK=16, 256 threads, 4x4 micro-tile. M = 8192 (grid.x = 128).
// ---------------------------------------------------------------------------
template <int K, int NOUT, bool SILU>
__global__ __launch_bounds__(256) void gemm_kernel(
    const float* __restrict__ A, const float* __restrict__ W,
    const float* __restrict__ bias, float* __restrict__ C)
{
    __shared__ float As[16][64];
    __shared__ float Bs[16][64];
    const int tid = threadIdx.x;
    const int m0 = blockIdx.x * 64;
    const int n0 = blockIdx.y * 64;
    const int tx = tid & 15;   // N dir
    const int ty = tid >> 4;   // M dir
    const int arow = tid >> 2, acol = (tid & 3) * 4;
    const int brow = tid >> 4, bcol = (tid & 15) * 4;

    float acc[4][4] = {};
    for (int k0 = 0; k0 < K; k0 += 16) {
        float4 av = *reinterpret_cast<const float4*>(
            A + (size_t)(m0 + arow) * K + k0 + acol);
        float4 bv = *reinterpret_cast<const float4*>(
            W + (size_t)(k0 + brow) * NOUT + n0 + bcol);
        As[acol + 0][arow] = av.x;
        As[acol + 1][arow] = av.y;
        As[acol + 2][arow] = av.z;
        As[acol + 3][arow] = av.w;
        *reinterpret_cast<float4*>(&Bs[brow][bcol]) = bv;
        __syncthreads();
        #pragma unroll
        for (int kk = 0; kk < 16; kk++) {
            float a[4], b[4];
            #pragma unroll
            for (int i = 0; i < 4; i++) a[i] = As[kk][ty * 4 + i];
            #pragma unroll
            for (int j = 0; j < 4; j++) b[j] = Bs[kk][tx * 4 + j];
            #pragma unroll
            for (int i = 0; i < 4; i++)
                #pragma unroll
                for (int j = 0; j < 4; j++)
                    acc[i][j] = fmaf(a[i], b[j], acc[i][j]);
        }
        __syncthreads();
    }
    #pragma unroll
    for (int i = 0; i < 4; i++) {
        int row = m0 + ty * 4 + i, col = n0 + tx * 4;
        float4 out;
        float* o = &out.x;
        #pragma unroll
        for (int j = 0; j < 4; j++) {
            float vv = acc[i][j] + bias[col + j];
            o[j] = SILU ? siluf(vv) : vv;
        }
        *reinterpret_cast<float4*>(C + (size_t)row * NOUT + col) = out;
    }
}

// ---------------------------------------------------------------------------
// k6: per-particle: z_new, log_q, rlog8 = HR@pr_w2+b, build X2=[z_new|h].
// One wave per particle.
// ---------------------------------------------------------------------------
__global__ __launch_bounds__(256) void k6_mid(
    const float* __restrict__ ZP, const float* __restrict__ HR,
    const float* __restrict__ eps_t, const float* __restrict__ pr_w2,
    const float* __restrict__ pr_b2, const float* __restrict__ h_t,
    float* __restrict__ z_new, float* __restrict__ rlog,
    float* __restrict__ log_q, float* __restrict__ X2)
{
    int wave = threadIdx.x >> 6, lane = threadIdx.x & 63;
    int p = blockIdx.x * 4 + wave;
    int b = p >> 9;
    float lq = 0.f;
    #pragma unroll
    for (int i = 0; i < 2; i++) {
        int d = lane + i * 64;
        float zm = ZP[(size_t)p * 256 + d];
        float zls = ZP[(size_t)p * 256 + 128 + d];
        zls = fminf(fmaxf(zls, -5.f), 2.f);
        float e = eps_t[(size_t)p * dL + d];
        float zn = zm + e * expf(zls);
        z_new[(size_t)p * dL + d] = zn;
        X2[(size_t)p * 384 + d] = zn;
        lq += -0.5f * e * e - zls;
    }
    // rlog8 partials: k = lane + kk*64
    float pr[8] = {};
    #pragma unroll
    for (int kk = 0; kk < 4; kk++) {
        int k = lane + kk * 64;
        float hv = HR[(size_t)p * 256 + k];
        #pragma unroll
        for (int r = 0; r < 8; r++) pr[r] = fmaf(hv, pr_w2[k * 8 + r], pr[r]);
    }
    #pragma unroll
    for (int o = 32; o > 0; o >>= 1) {
        lq += __shfl_down(lq, o);
        #pragma unroll
        for (int r = 0; r < 8; r++) pr[r] += __shfl_down(pr[r], o);
    }
    if (lane == 0) {
        log_q[p] = lq - dL * 0.5f * LOG2PI;
        #pragma unroll
        for (int r = 0; r < 8; r++) rlog[p * 8 + r] = pr[r] + pr_b2[r];
    }
    const float* hb = h_t + b * dM;
    #pragma unroll
    for (int i = 0; i < 4; i++) {
        int c = lane + i * 64;
        X2[(size_t)p * 384 + 128 + c] = hb[c];
    }
}

// ---------------------------------------------------------------------------
// k9: per-particle: em = E2 @ oe_w3 + b; pred/lsb; rp_new; sigma; ll; log_w.
// One wave per particle.
// ---------------------------------------------------------------------------
__global__ __launch_bounds__(256) void k9_logw(
    const float* __restrict__ E2, const float* __restrict__ rlog,
    const float* __restrict__ log_q, const float* __restrict__ oe_w3,
    const float* __restrict__ oe_b3, const float* __restrict__ obs_t,
    const float* __restrict__ log_obs_scale, float* __restrict__ log_w)
{
    int wave = threadIdx.x >> 6, lane = threadIdx.x & 63;
    int p = blockIdx.x * 4 + wave;
    int b = p >> 9;
    float p0 = 0.f, p1 = 0.f;
    #pragma unroll
    for (int i = 0; i < 2; i++) {
        int k = lane + i * 64;
        float e = E2[(size_t)p * 128 + k];
        p0 = fmaf(e, oe_w3[k * 2 + 0], p0);
        p1 = fmaf(e, oe_w3[k * 2 + 1], p1);
    }
    #pragma unroll
    for (int o = 32; o > 0; o >>= 1) {
        p0 += __shfl_down(p0, o);
        p1 += __shfl_down(p1, o);
    }
    if (lane == 0) {
        float pred = p0 + oe_b3[0];
        float lsb  = p1 + oe_b3[1];
        float rv[8], m = 0.f;   // padded zeros participate in max
        #pragma unroll
        for (int r = 0; r < 8; r++) { rv[r] = rlog[p * 8 + r]; m = fmaxf(m, rv[r]); }
        float denom = (Kt - 8) * expf(-m);
        #pragma unroll
        for (int r = 0; r < 8; r++) denom += expf(rv[r] - m);
        float sdot = 0.f;
        #pragma unroll
        for (int r = 0; r < 8; r++)
            sdot += (expf(rv[r] - m) / denom) * softplusf(log_obs_scale[r]);
        float sigma = fminf(fmaxf(softplusf(lsb) * sdot, 0.1f), 5.f);
        float y = obs_t[b];
        float dd = (y - pred) / sigma;
        float ll = -0.5f * dd * dd - logf(sigma) - 0.5f * LOG2PI;
        log_w[p] = ll - log_q[p];
    }
}

// ---------------------------------------------------------------------------
// k10: per-batch softmax over N + weighted mean of z_new -> out (B x 128)
// ---------------------------------------------------------------------------
__global__ __launch_bounds__(256) void k10_mean(
    const float* __restrict__ log_w, const float* __restrict__ z_new,
    float* __restrict__ out_t)
{
    int b = blockIdx.x, tid = threadIdx.x;
    __shared__ float sw[512];
    __shared__ float red[256];
    float lm = -1e30f;
    for (int n = tid; n < Nn; n += 256) lm = fmaxf(lm, log_w[b * Nn + n]);
    red[tid] = lm; __syncthreads();
    for (int s = 128; s > 0; s >>= 1) {
        if (tid < s) red[tid] = fmaxf(red[tid], red[tid + s]);
        __syncthreads();
    }
    float m = red[0]; __syncthreads();
    float ps = 0.f;
    for (int n = tid; n < Nn; n += 256) {
        float e = expf(log_w[b * Nn + n] - m);
        sw[n] = e; ps += e;
    }
    red[tid] = ps; __syncthreads();
    for (int s = 128; s > 0; s >>= 1) {
        if (tid < s) red[tid] += red[tid + s];
        __syncthreads();
    }
    float inv = 1.f / red[0];
    if (tid < dL) {
        float acc = 0.f;
        for (int n = 0; n < Nn; n++)
            acc = fmaf(sw[n], z_new[(size_t)(b * Nn + n) * dL + tid], acc);
        out_t[b * dL + tid] = acc * inv;
    }
}

// ---------------------------------------------------------------------------
// k11: per-row (b,i) max & inv-sum of exp((log_w[j]+g[i,j])/TEMP). Wave/row.
// ---------------------------------------------------------------------------
__global__ __launch_bounds__(256) void k11_rowstats(
    const float* __restrict__ log_w, const float* __restrict__ u_t,
    float* __restrict__ rowm, float* __restrict__ rowinv)
{
    int wave = threadIdx.x >> 6, lane = threadIdx.x & 63;
    int row = blockIdx.x * 4 + wave;   // row = b*512 + i
    int b = row >> 9;
    float q[8], m = -1e30f;
    #pragma unroll
    for (int jj = 0; jj < 8; jj++) {
        int j = jj * 64 + lane;
        float u = u_t[(size_t)row * Nn + j];
        float g = -logf(-logf(u + 1e-10f) + 1e-10f);
        q[jj] = (log_w[b * Nn + j] + g) * 2.0f;   // 1/TEMP = 2
        m = fmaxf(m, q[jj]);
    }
    #pragma unroll
    for (int o = 1; o < 64; o <<= 1) m = fmaxf(m, __shfl_xor(m, o));
    float s = 0.f;
    #pragma unroll
    for (int jj = 0; jj < 8; jj++) s += expf(q[jj] - m);
    #pragma unroll
    for (int o = 1; o < 64; o <<= 1) s += __shfl_xor(s, o);
    if (lane == 0) { rowm[row] = m; rowinv[row] = 1.f / s; }
}

// ---------------------------------------------------------------------------
// k12: resampling GEMM with A computed on the fly. 4 rows per block (4 waves),
// V tile = [z_new | rlog8] (136 cols) staged in LDS. Writes carries z, rl.
// ---------------------------------------------------------------------------
__global__ __launch_bounds__(256) void k12_resample(
    const float* __restrict__ log_w, const float* __restrict__ u_t,
    const float* __restrict__ z_new, const float* __restrict__ rlog,
    const float* __restrict__ rowm, const float* __restrict__ rowinv,
    float* __restrict__ z, float* __restrict__ rl)
{
    __shared__ float Vs[64][136];
    __shared__ float as_[4][64];
    int tid = threadIdx.x;
    int wave = tid >> 6, lane = tid & 63;
    int row = blockIdx.x * 4 + wave;
    int b = row >> 9;
    float m = rowm[row], inv = rowinv[row];
    float acc0 = 0.f, acc1 = 0.f, acc2 = 0.f;
    for (int jt = 0; jt < 8; jt++) {
        int jbase = jt * 64;
        for (int idx = tid; idx < 64 * 136; idx += 256) {
            int r = idx / 136, c = idx % 136;
            int gp = b * Nn + jbase + r;
            Vs[r][c] = (c < 128) ? z_new[(size_t)gp * dL + c]
                                 : rlog[gp * 8 + (c - 128)];
        }
        int j = jbase + lane;
        float u = u_t[(size_t)row * Nn + j];
        float g = -logf(-logf(u + 1e-10f) + 1e-10f);
        as_[wave][lane] = expf((log_w[b * Nn + j] + g) * 2.0f - m) * inv;
        __syncthreads();
        #pragma unroll 8
        for (int jj = 0; jj < 64; jj++) {
            float a = as_[wave][jj];
            acc0 = fmaf(a, Vs[jj][lane], acc0);
            acc1 = fmaf(a, Vs[jj][lane + 64], acc1);
            if (lane < 8) acc2 = fmaf(a, Vs[jj][128 + lane], acc2);
        }
        __syncthreads();
    }
    z[(size_t)row * dL + lane] = acc0;
    z[(size_t)row * dL + lane + 64] = acc1;
    if (lane < 8) rl[row * Kt + lane] = acc2;
    if (lane >= 8 && lane < Kt) rl[row * Kt + lane] = 0.f;
}

// ---------------------------------------------------------------------------
extern "C" void kernel_launch(void* const* d_in, const int* in_sizes, int n_in,
                              void* d_out, int out_size, void* d_ws, size_t ws_size,
                              hipStream_t stream)
{
    const float* obs      = (const float*)d_in[0];   // (T,B)
    const float* h_seq    = (const float*)d_in[1];   // (T,B,256)
    const float* z0       = (const float*)d_in[2];   // (B,N,128)
    const float* rl0      = (const float*)d_in[3];   // (B,N,18)
    const float* eps      = (const float*)d_in[4];   // (T,B,N,128)
    const float* gum      = (const float*)d_in[5];   // (T,B,N,N)
    const float* pe_emb   = (const float*)d_in[6];   // (18,32)
    const float* pz_w1    = (const float*)d_in[7];
    const float* pz_b1    = (const float*)d_in[8];
    const float* pz_w2    = (const float*)d_in[9];
    const float* pz_b2    = (const float*)d_in[10];
    const float* pz_w3    = (const float*)d_in[11];
    const float* pz_b3    = (const float*)d_in[12];
    const float* pr_w1    = (const float*)d_in[13];
    const float* pr_b1    = (const float*)d_in[14];
    const float* pr_w2    = (const float*)d_in[15];
    const float* pr_b2    = (const float*)d_in[16];
    const float* oe_w1    = (const float*)d_in[17];
    const float* oe_b1    = (const float*)d_in[18];
    const float* oe_w2    = (const float*)d_in[19];
    const float* oe_b2    = (const float*)d_in[20];
    const float* oe_w3    = (const float*)d_in[21];
    const float* oe_b3    = (const float*)d_in[22];
    const float* los      = (const float*)d_in[23];  // log_obs_scale (18)
    float* out = (float*)d_out;

    // workspace layout (floats)
    float* W = (float*)d_ws;
    float* z      = W;                    // P*128
    float* rl     = z + (size_t)P * dL;   // P*18
    float* X      = rl + (size_t)P * Kt;  // P*416 (X2 aliases, stride 384)
    float* bufB   = X + (size_t)P * DIN;  // P*256  H1 then ZP
    float* bufC   = bufB + (size_t)P * 256; // P*256  H2 then E1
    float* bufD   = bufC + (size_t)P * 256; // P*256  HR then E2(stride128)
    float* z_new  = bufD + (size_t)P * 256; // P*128
    float* rlog   = z_new + (size_t)P * dL; // P*8
    float* log_q  = rlog + (size_t)P * 8;   // P
    float* log_w  = log_q + P;              // P
    float* rowm   = log_w + P;              // P
    float* rowinv = rowm + P;               // P

    // init carries
    hipMemcpyAsync(z, z0, (size_t)P * dL * sizeof(float),
                   hipMemcpyDeviceToDevice, stream);
    hipMemcpyAsync(rl, rl0, (size_t)P * Kt * sizeof(float),
                   hipMemcpyDeviceToDevice, stream);

    for (int t = 0; t < Tt; t++) {
        const float* h_t   = h_seq + (size_t)t * Bb * dM;
        const float* obs_t = obs + (size_t)t * Bb;
        const float* eps_t = eps + (size_t)t * P * dL;
        const float* u_t   = gum + (size_t)t * P * Nn;
        float* out_t = out + (size_t)t * Bb * dL;

        k1_build_inp<<<P / 4, 256, 0, stream>>>(rl, z, h_t, pe_emb, X);
        gemm_kernel<416, 256, true><<<dim3(P / 64, 4), 256, 0, stream>>>(
            X, pz_w1, pz_b1, bufB);                    // H1
        gemm_kernel<256, 256, true><<<dim3(P / 64, 4), 256, 0, stream>>>(
            bufB, pz_w2, pz_b2, bufC);                 // H2
        gemm_kernel<256, 256, false><<<dim3(P / 64, 4), 256, 0, stream>>>(
            bufC, pz_w3, pz_b3, bufB);                 // ZP (overwrites H1)
        gemm_kernel<416, 256, true><<<dim3(P / 64, 4), 256, 0, stream>>>(
            X, pr_w1, pr_b1, bufD);                    // HR
        k6_mid<<<P / 4, 256, 0, stream>>>(bufB, bufD, eps_t, pr_w2, pr_b2,
                                          h_t, z_new, rlog, log_q, X);  // X2 aliases X
        gemm_kernel<384, 256, true><<<dim3(P / 64, 4), 256, 0, stream>>>(
            X, oe_w1, oe_b1, bufC);                    // E1 (overwrites H2)
        gemm_kernel<256, 128, true><<<dim3(P / 64, 2), 256, 0, stream>>>(
            bufC, oe_w2, oe_b2, bufD);                 // E2 (overwrites HR)
        k9_logw<<<P / 4, 256, 0, stream>>>(bufD, rlog, log_q, oe_w3, oe_b3,
                                           obs_t, los, log_w);
        k10_mean<<<Bb, 256, 0, stream>>>(log_w, z_new, out_t);
        k11_rowstats<<<P / 4, 256, 0, stream>>>(log_w, u_t, rowm, rowinv);
        k12_resample<<<P / 4, 256, 0, stream>>>(log_w, u_t, z_new, rlog,
                                                rowm, rowinv, z, rl);
    }
}

// Round 4
// 4071.842 us; speedup vs baseline: 1.5042x; 1.5042x over previous
//
#include <hip/hip_runtime.h>
#include <hip/hip_bf16.h>
#include <math.h>

#define LOG2PI 1.8378770664093453f

// Problem dims
constexpr int Bb = 16, Nn = 512, Tt = 16;
constexpr int dL = 128, dM = 256, dE = 32, Kt = 18;
constexpr int P = Bb * Nn;          // 8192 particles
constexpr int DIN = 416;            // dM + dL + dE

typedef __attribute__((ext_vector_type(8))) _Float16 f16x8;
typedef __attribute__((ext_vector_type(4))) float f32x4;

__device__ __forceinline__ float siluf(float x) { return x / (1.f + expf(-x)); }
__device__ __forceinline__ float softplusf(float x) {
    return (x > 20.f) ? x : log1pf(expf(x));
}
__device__ __forceinline__ short f2h(float x) {
    _Float16 h = (_Float16)x;
    short s;
    __builtin_memcpy(&s, &h, 2);
    return s;
}
__device__ __forceinline__ float h2f(short s) {
    _Float16 h;
    __builtin_memcpy(&h, &s, 2);
    return (float)h;
}
// split x into hi (fp16) + lo (fp16 of residual); |x - hi - lo| <= 2^-22 |x|
__device__ __forceinline__ void split2(float x, short& hi, short& lo) {
    hi = f2h(x);
    lo = f2h(x - h2f(hi));
}
__device__ __forceinline__ f32x4 mfma16(f16x8 a, f16x8 b, f32x4 c) {
    return __builtin_amdgcn_mfma_f32_16x16x32_f16(a, b, c, 0, 0, 0);
}

// ---------------------------------------------------------------------------
// kT: weight convert+transpose+split: out_{hi,lo}[n*K+k] = split(in[k*N+n])
// ---------------------------------------------------------------------------
__global__ __launch_bounds__(256) void kT_transpose(
    const float* __restrict__ in, short* __restrict__ out_hi,
    short* __restrict__ out_lo, int K, int N)
{
    int idx = blockIdx.x * 256 + threadIdx.x;
    if (idx < K * N) {
        int n = idx / K, k = idx % K;
        short hi, lo;
        split2(in[(size_t)k * N + n], hi, lo);
        out_hi[idx] = hi;
        out_lo[idx] = lo;
    }
}

// ---------------------------------------------------------------------------
// k1: build input X = [h_exp | z | remb]  (P x 416) split fp16. Wave/particle.
// ---------------------------------------------------------------------------
__global__ __launch_bounds__(256) void k1_build_inp(
    const float* __restrict__ rl, const float* __restrict__ z,
    const float* __restrict__ h_t, const float* __restrict__ pe_emb,
    short* __restrict__ Xhi, short* __restrict__ Xlo)
{
    int wave = threadIdx.x >> 6, lane = threadIdx.x & 63;
    int p = blockIdx.x * 4 + wave;
    int b = p >> 9;
    float v[Kt];
    float m = -1e30f;
    #pragma unroll
    for (int k = 0; k < Kt; k++) { v[k] = rl[p * Kt + k]; m = fmaxf(m, v[k]); }
    float denom = 0.f;
    #pragma unroll
    for (int k = 0; k < Kt; k++) denom += expf(v[k] - m);
    float remb = 0.f;
    if (lane < dE) {
        #pragma unroll
        for (int k = 0; k < 8; k++)
            remb += (expf(v[k] - m) / denom) * pe_emb[k * dE + lane];
    }
    const float* hb = h_t + b * dM;
    size_t base = (size_t)p * DIN;
    float vals[7];
    vals[0] = hb[lane];
    vals[1] = hb[64 + lane];
    vals[2] = hb[128 + lane];
    vals[3] = hb[192 + lane];
    vals[4] = z[(size_t)p * dL + lane];
    vals[5] = z[(size_t)p * dL + 64 + lane];
    vals[6] = remb;
    #pragma unroll
    for (int i = 0; i < 6; i++) {
        short hi, lo;
        split2(vals[i], hi, lo);
        Xhi[base + i * 64 + lane] = hi;
        Xlo[base + i * 64 + lane] = lo;
    }
    if (lane < dE) {
        short hi, lo;
        split2(vals[6], hi, lo);
        Xhi[base + 384 + lane] = hi;
        Xlo[base + 384 + lane] = lo;
    }
}

// ---------------------------------------------------------------------------
// Split-precision MFMA GEMM: C = act(A @ Wt^T + bias), fp32-class accuracy.
// A given as (Ahi, Alo) fp16 planes [M][K]; Wt as (Whi, Wlo) [NOUT][K].
// acc += Ahi*Whi + Ahi*Wlo + Alo*Whi  (lo*lo dropped, ~2^-22)
// Block 256 thr = 4 waves; wave = 16 rows x 64 cols (4 n-frags). LDS-free.
// MODE 0: silu -> split fp16 out (Chi, Clo). MODE 1: raw -> f32 out (Chi).
// ---------------------------------------------------------------------------
template <int K, int NOUT, int MODE>
__global__ __launch_bounds__(256) void mfma_gemm(
    const short* __restrict__ Ahi, const short* __restrict__ Alo,
    const short* __restrict__ Whi, const short* __restrict__ Wlo,
    const float* __restrict__ bias, void* __restrict__ Chi,
    short* __restrict__ Clo)
{
    int tid = threadIdx.x;
    int w = tid >> 6, l = tid & 63;
    int lr = l & 15, lk = (l >> 4) * 8;
    int m0 = blockIdx.x * 64 + w * 16;
    int n0 = blockIdx.y * 64;
    size_t aoff = (size_t)(m0 + lr) * K + lk;
    size_t boff = (size_t)(n0 + lr) * K + lk;
    f32x4 acc[4];
    #pragma unroll
    for (int nf = 0; nf < 4; nf++) acc[nf] = f32x4{0.f, 0.f, 0.f, 0.f};
    for (int k0 = 0; k0 < K; k0 += 32) {
        f16x8 ah = *reinterpret_cast<const f16x8*>(Ahi + aoff + k0);
        f16x8 al = *reinterpret_cast<const f16x8*>(Alo + aoff + k0);
        #pragma unroll
        for (int nf = 0; nf < 4; nf++) {
            f16x8 bh = *reinterpret_cast<const f16x8*>(Whi + boff + (size_t)nf * 16 * K + k0);
            f16x8 bl = *reinterpret_cast<const f16x8*>(Wlo + boff + (size_t)nf * 16 * K + k0);
            acc[nf] = mfma16(ah, bh, acc[nf]);
            acc[nf] = mfma16(ah, bl, acc[nf]);
            acc[nf] = mfma16(al, bh, acc[nf]);
        }
    }
    int orow = (l >> 4) * 4;
    #pragma unroll
    for (int nf = 0; nf < 4; nf++) {
        int col = n0 + nf * 16 + lr;
        float bv = bias[col];
        #pragma unroll
        for (int r = 0; r < 4; r++) {
            int row = m0 + orow + r;
            float vv = acc[nf][r] + bv;
            if constexpr (MODE == 0) {
                float sv = siluf(vv);
                short hi, lo;
                split2(sv, hi, lo);
                ((short*)Chi)[(size_t)row * NOUT + col] = hi;
                Clo[(size_t)row * NOUT + col] = lo;
            } else {
                ((float*)Chi)[(size_t)row * NOUT + col] = vv;
            }
        }
    }
}

// ---------------------------------------------------------------------------
// k6: per-particle: z_new, log_q, rlog8 = HR@pr_w2+b, X2=[z_new|h] split,
// Vt scatter (split planes). One wave per particle.
// ---------------------------------------------------------------------------
__global__ __launch_bounds__(256) void k6_mid(
    const float* __restrict__ ZP, const short* __restrict__ HRhi,
    const short* __restrict__ HRlo,
    const float* __restrict__ eps_t, const float* __restrict__ pr_w2,
    const float* __restrict__ pr_b2, const float* __restrict__ h_t,
    float* __restrict__ z_new, float* __restrict__ rlog,
    float* __restrict__ log_q, short* __restrict__ X2hi,
    short* __restrict__ X2lo, short* __restrict__ vthi,
    short* __restrict__ vtlo)
{
    int wave = threadIdx.x >> 6, lane = threadIdx.x & 63;
    int p = blockIdx.x * 4 + wave;
    int b = p >> 9, i = p & 511;
    float lq = 0.f;
    #pragma unroll
    for (int ii = 0; ii < 2; ii++) {
        int d = lane + ii * 64;
        float zm = ZP[(size_t)p * 256 + d];
        float zls = fminf(fmaxf(ZP[(size_t)p * 256 + 128 + d], -5.f), 2.f);
        float e = eps_t[(size_t)p * dL + d];
        float zn = zm + e * expf(zls);
        z_new[(size_t)p * dL + d] = zn;
        short hi, lo;
        split2(zn, hi, lo);
        X2hi[(size_t)p * 384 + d] = hi;
        X2lo[(size_t)p * 384 + d] = lo;
        vthi[((size_t)b * 144 + d) * 512 + i] = hi;
        vtlo[((size_t)b * 144 + d) * 512 + i] = lo;
        lq += -0.5f * e * e - zls;
    }
    // rlog8 partials (fp32 reconstruct of HR)
    float pr[8] = {};
    #pragma unroll
    for (int kk = 0; kk < 4; kk++) {
        int k = lane + kk * 64;
        float hv = h2f(HRhi[(size_t)p * 256 + k]) + h2f(HRlo[(size_t)p * 256 + k]);
        #pragma unroll
        for (int r = 0; r < 8; r++) pr[r] = fmaf(hv, pr_w2[k * 8 + r], pr[r]);
    }
    #pragma unroll
    for (int o = 32; o > 0; o >>= 1) {
        lq += __shfl_down(lq, o);
        #pragma unroll
        for (int r = 0; r < 8; r++) pr[r] += __shfl_down(pr[r], o);
    }
    if (lane == 0) {
        log_q[p] = lq - dL * 0.5f * LOG2PI;
        #pragma unroll
        for (int r = 0; r < 8; r++) {
            float prv = pr[r] + pr_b2[r];
            rlog[p * 8 + r] = prv;
            short hi, lo;
            split2(prv, hi, lo);
            vthi[((size_t)b * 144 + 128 + r) * 512 + i] = hi;
            vtlo[((size_t)b * 144 + 128 + r) * 512 + i] = lo;
        }
    }
    if (lane < 8) {
        vthi[((size_t)b * 144 + 136 + lane) * 512 + i] = 0;
        vtlo[((size_t)b * 144 + 136 + lane) * 512 + i] = 0;
    }
    const float* hb = h_t + b * dM;
    #pragma unroll
    for (int ii = 0; ii < 4; ii++) {
        int c = lane + ii * 64;
        short hi, lo;
        split2(hb[c], hi, lo);
        X2hi[(size_t)p * 384 + 128 + c] = hi;
        X2lo[(size_t)p * 384 + 128 + c] = lo;
    }
}

// ---------------------------------------------------------------------------
// k9: per-particle: em = E2 @ oe_w3 + b; sigma; ll; log_w = ll - log_q.
// ---------------------------------------------------------------------------
__global__ __launch_bounds__(256) void k9_logw(
    const short* __restrict__ E2hi, const short* __restrict__ E2lo,
    const float* __restrict__ rlog,
    const float* __restrict__ log_q, const float* __restrict__ oe_w3,
    const float* __restrict__ oe_b3, const float* __restrict__ obs_t,
    const float* __restrict__ log_obs_scale, float* __restrict__ log_w)
{
    int wave = threadIdx.x >> 6, lane = threadIdx.x & 63;
    int p = blockIdx.x * 4 + wave;
    int b = p >> 9;
    float p0 = 0.f, p1 = 0.f;
    #pragma unroll
    for (int i = 0; i < 2; i++) {
        int k = lane + i * 64;
        float e = h2f(E2hi[(size_t)p * 128 + k]) + h2f(E2lo[(size_t)p * 128 + k]);
        p0 = fmaf(e, oe_w3[k * 2 + 0], p0);
        p1 = fmaf(e, oe_w3[k * 2 + 1], p1);
    }
    #pragma unroll
    for (int o = 32; o > 0; o >>= 1) {
        p0 += __shfl_down(p0, o);
        p1 += __shfl_down(p1, o);
    }
    if (lane == 0) {
        float pred = p0 + oe_b3[0];
        float lsb  = p1 + oe_b3[1];
        float rv[8], m = 0.f;   // padded zeros participate in max
        #pragma unroll
        for (int r = 0; r < 8; r++) { rv[r] = rlog[p * 8 + r]; m = fmaxf(m, rv[r]); }
        float denom = (Kt - 8) * expf(-m);
        #pragma unroll
        for (int r = 0; r < 8; r++) denom += expf(rv[r] - m);
        float sdot = 0.f;
        #pragma unroll
        for (int r = 0; r < 8; r++)
            sdot += (expf(rv[r] - m) / denom) * softplusf(log_obs_scale[r]);
        float sigma = fminf(fmaxf(softplusf(lsb) * sdot, 0.1f), 5.f);
        float y = obs_t[b];
        float dd = (y - pred) / sigma;
        float ll = -0.5f * dd * dd - logf(sigma) - 0.5f * LOG2PI;
        log_w[p] = ll - log_q[p];
    }
}

// ---------------------------------------------------------------------------
// k10: per-batch softmax over N + weighted mean of z_new -> out (B x 128)
// ---------------------------------------------------------------------------
__global__ __launch_bounds__(256) void k10_mean(
    const float* __restrict__ log_w, const float* __restrict__ z_new,
    float* __restrict__ out_t)
{
    int b = blockIdx.x, tid = threadIdx.x;
    __shared__ float sw[512];
    __shared__ float red[256];
    float lm = -1e30f;
    for (int n = tid; n < Nn; n += 256) lm = fmaxf(lm, log_w[b * Nn + n]);
    red[tid] = lm; __syncthreads();
    for (int s = 128; s > 0; s >>= 1) {
        if (tid < s) red[tid] = fmaxf(red[tid], red[tid + s]);
        __syncthreads();
    }
    float m = red[0]; __syncthreads();
    float ps = 0.f;
    for (int n = tid; n < Nn; n += 256) {
        float e = expf(log_w[b * Nn + n] - m);
        sw[n] = e; ps += e;
    }
    red[tid] = ps; __syncthreads();
    for (int s = 128; s > 0; s >>= 1) {
        if (tid < s) red[tid] += red[tid + s];
        __syncthreads();
    }
    float inv = 1.f / red[0];
    if (tid < dL) {
        float acc = 0.f;
        for (int n = 0; n < Nn; n++)
            acc = fmaf(sw[n], z_new[(size_t)(b * Nn + n) * dL + tid], acc);
        out_t[b * dL + tid] = acc * inv;
    }
}

// ---------------------------------------------------------------------------
// k11: per-row softmax((log_w+g)/TEMP) -> split A planes (P x 512). Wave/row.
// Also zeroes rl cols 8..17 for next step.
// ---------------------------------------------------------------------------
__global__ __launch_bounds__(256) void k11_weights(
    const float* __restrict__ log_w, const float* __restrict__ u_t,
    short* __restrict__ Ahi, short* __restrict__ Alo, float* __restrict__ rl)
{
    int wave = threadIdx.x >> 6, lane = threadIdx.x & 63;
    int row = blockIdx.x * 4 + wave;   // row = b*512 + i
    int b = row >> 9;
    float q[8], m = -1e30f;
    #pragma unroll
    for (int jj = 0; jj < 8; jj++) {
        int j = jj * 64 + lane;
        float u = u_t[(size_t)row * Nn + j];
        float g = -logf(-logf(u + 1e-10f) + 1e-10f);
        q[jj] = (log_w[b * Nn + j] + g) * 2.0f;   // 1/TEMP = 2
        m = fmaxf(m, q[jj]);
    }
    #pragma unroll
    for (int o = 1; o < 64; o <<= 1) m = fmaxf(m, __shfl_xor(m, o));
    float e[8], s = 0.f;
    #pragma unroll
    for (int jj = 0; jj < 8; jj++) { e[jj] = expf(q[jj] - m); s += e[jj]; }
    #pragma unroll
    for (int o = 1; o < 64; o <<= 1) s += __shfl_xor(s, o);
    float inv = 1.f / s;
    #pragma unroll
    for (int jj = 0; jj < 8; jj++) {
        short hi, lo;
        split2(e[jj] * inv, hi, lo);
        Ahi[(size_t)row * Nn + jj * 64 + lane] = hi;
        Alo[(size_t)row * Nn + jj * 64 + lane] = lo;
    }
    if (lane < 10) rl[row * Kt + 8 + lane] = 0.f;
}

// ---------------------------------------------------------------------------
// k12: resample split MFMA GEMM: C[512 x 144] = A[512 x 512] @ V[512 x 144]
// per batch. V via vt[b][col][particle] split planes. Writes z, rl carries.
// grid (16, 8, 3); block 256 (4 waves, wave = 16 rows x 48 cols).
// ---------------------------------------------------------------------------
__global__ __launch_bounds__(256) void k12_mfma(
    const short* __restrict__ Ahi, const short* __restrict__ Alo,
    const short* __restrict__ vthi, const short* __restrict__ vtlo,
    float* __restrict__ z, float* __restrict__ rl)
{
    int tid = threadIdx.x;
    int w = tid >> 6, l = tid & 63;
    int lr = l & 15, lk = (l >> 4) * 8;
    int b = blockIdx.x;
    int m0 = blockIdx.y * 64 + w * 16;
    int n0 = blockIdx.z * 48;
    size_t aoff = ((size_t)(b * 512 + m0 + lr)) * 512 + lk;
    size_t voff = ((size_t)b * 144 + n0 + lr) * 512 + lk;
    f32x4 acc[3];
    #pragma unroll
    for (int nf = 0; nf < 3; nf++) acc[nf] = f32x4{0.f, 0.f, 0.f, 0.f};
    for (int k0 = 0; k0 < 512; k0 += 32) {
        f16x8 ah = *reinterpret_cast<const f16x8*>(Ahi + aoff + k0);
        f16x8 al = *reinterpret_cast<const f16x8*>(Alo + aoff + k0);
        #pragma unroll
        for (int nf = 0; nf < 3; nf++) {
            f16x8 bh = *reinterpret_cast<const f16x8*>(vthi + voff + (size_t)nf * 16 * 512 + k0);
            f16x8 bl = *reinterpret_cast<const f16x8*>(vtlo + voff + (size_t)nf * 16 * 512 + k0);
            acc[nf] = mfma16(ah, bh, acc[nf]);
            acc[nf] = mfma16(ah, bl, acc[nf]);
            acc[nf] = mfma16(al, bh, acc[nf]);
        }
    }
    int orow = (l >> 4) * 4;
    #pragma unroll
    for (int nf = 0; nf < 3; nf++) {
        int col = n0 + nf * 16 + lr;
        #pragma unroll
        for (int r = 0; r < 4; r++) {
            int gp = b * 512 + m0 + orow + r;
            float v = acc[nf][r];
            if (col < 128) z[(size_t)gp * dL + col] = v;
            else if (col < 136) rl[gp * Kt + (col - 128)] = v;
        }
    }
}

// ---------------------------------------------------------------------------
extern "C" void kernel_launch(void* const* d_in, const int* in_sizes, int n_in,
                              void* d_out, int out_size, void* d_ws, size_t ws_size,
                              hipStream_t stream)
{
    const float* obs      = (const float*)d_in[0];   // (T,B)
    const float* h_seq    = (const float*)d_in[1];   // (T,B,256)
    const float* z0       = (const float*)d_in[2];   // (B,N,128)
    const float* rl0      = (const float*)d_in[3];   // (B,N,18)
    const float* eps      = (const float*)d_in[4];   // (T,B,N,128)
    const float* gum      = (const float*)d_in[5];   // (T,B,N,N)
    const float* pe_emb   = (const float*)d_in[6];   // (18,32)
    const float* pz_w1    = (const float*)d_in[7];
    const float* pz_b1    = (const float*)d_in[8];
    const float* pz_w2    = (const float*)d_in[9];
    const float* pz_b2    = (const float*)d_in[10];
    const float* pz_w3    = (const float*)d_in[11];
    const float* pz_b3    = (const float*)d_in[12];
    const float* pr_w1    = (const float*)d_in[13];
    const float* pr_b1    = (const float*)d_in[14];
    const float* pr_w2    = (const float*)d_in[15];
    const float* pr_b2    = (const float*)d_in[16];
    const float* oe_w1    = (const float*)d_in[17];
    const float* oe_b1    = (const float*)d_in[18];
    const float* oe_w2    = (const float*)d_in[19];
    const float* oe_b2    = (const float*)d_in[20];
    const float* oe_w3    = (const float*)d_in[21];
    const float* oe_b3    = (const float*)d_in[22];
    const float* los      = (const float*)d_in[23];  // log_obs_scale (18)
    float* out = (float*)d_out;

    // workspace layout
    char* base = (char*)d_ws;
    float* z      = (float*)base;  base += (size_t)P * dL * 4;        // 4 MB
    float* rl     = (float*)base;  base += (size_t)P * Kt * 4;        // 0.59 MB
    short* Xhi    = (short*)base;  base += (size_t)P * DIN * 2;       // 6.8 MB
    short* Xlo    = (short*)base;  base += (size_t)P * DIN * 2;       // 6.8 MB
    short* H1hi   = (short*)base;  base += (size_t)P * 256 * 2;       // 4 MB
    short* H1lo   = (short*)base;  base += (size_t)P * 256 * 2;       // 4 MB
    short* H2hi   = (short*)base;  base += (size_t)P * 256 * 2;       // 4 MB
    short* H2lo   = (short*)base;  base += (size_t)P * 256 * 2;       // 4 MB
    float* ZPf    = (float*)base;  base += (size_t)P * 256 * 4;       // 8 MB
    short* HRhi   = (short*)base;  base += (size_t)P * 256 * 2;       // 4 MB
    short* HRlo   = (short*)base;  base += (size_t)P * 256 * 2;       // 4 MB
    float* z_new  = (float*)base;  base += (size_t)P * dL * 4;        // 4 MB
    float* rlog   = (float*)base;  base += (size_t)P * 8 * 4;
    float* log_q  = (float*)base;  base += (size_t)P * 4;
    float* log_w  = (float*)base;  base += (size_t)P * 4;
    short* vthi   = (short*)base;  base += (size_t)16 * 144 * 512 * 2; // 2.25 MB
    short* vtlo   = (short*)base;  base += (size_t)16 * 144 * 512 * 2; // 2.25 MB
    short* w_pz1h = (short*)base;  base += (size_t)416 * 256 * 2;
    short* w_pz1l = (short*)base;  base += (size_t)416 * 256 * 2;
    short* w_pz2h = (short*)base;  base += (size_t)256 * 256 * 2;
    short* w_pz2l = (short*)base;  base += (size_t)256 * 256 * 2;
    short* w_pz3h = (short*)base;  base += (size_t)256 * 256 * 2;
    short* w_pz3l = (short*)base;  base += (size_t)256 * 256 * 2;
    short* w_pr1h = (short*)base;  base += (size_t)416 * 256 * 2;
    short* w_pr1l = (short*)base;  base += (size_t)416 * 256 * 2;
    short* w_oe1h = (short*)base;  base += (size_t)384 * 256 * 2;
    short* w_oe1l = (short*)base;  base += (size_t)384 * 256 * 2;
    short* w_oe2h = (short*)base;  base += (size_t)256 * 128 * 2;
    short* w_oe2l = (short*)base;  base += (size_t)256 * 128 * 2;
    // aliases (dead-buffer reuse):
    short* X2hi = Xhi;            // X dead once X2 built (stride 384 <= 416)
    short* X2lo = Xlo;
    short* E1hi = H1hi;           // H1 dead after pz2
    short* E1lo = H1lo;
    short* E2hi = H2hi;           // H2 dead after pz3
    short* E2lo = H2lo;
    short* Ahi  = H1hi;           // spans H1hi+H1lo (8 MB = P*512*2); dead at k11
    short* Alo  = H2hi;           // spans H2hi+H2lo

    // one-time weight transposes+splits
    kT_transpose<<<(416 * 256 + 255) / 256, 256, 0, stream>>>(pz_w1, w_pz1h, w_pz1l, 416, 256);
    kT_transpose<<<(256 * 256 + 255) / 256, 256, 0, stream>>>(pz_w2, w_pz2h, w_pz2l, 256, 256);
    kT_transpose<<<(256 * 256 + 255) / 256, 256, 0, stream>>>(pz_w3, w_pz3h, w_pz3l, 256, 256);
    kT_transpose<<<(416 * 256 + 255) / 256, 256, 0, stream>>>(pr_w1, w_pr1h, w_pr1l, 416, 256);
    kT_transpose<<<(384 * 256 + 255) / 256, 256, 0, stream>>>(oe_w1, w_oe1h, w_oe1l, 384, 256);
    kT_transpose<<<(256 * 128 + 255) / 256, 256, 0, stream>>>(oe_w2, w_oe2h, w_oe2l, 256, 128);

    // init carries
    hipMemcpyAsync(z, z0, (size_t)P * dL * sizeof(float),
                   hipMemcpyDeviceToDevice, stream);
    hipMemcpyAsync(rl, rl0, (size_t)P * Kt * sizeof(float),
                   hipMemcpyDeviceToDevice, stream);

    for (int t = 0; t < Tt; t++) {
        const float* h_t   = h_seq + (size_t)t * Bb * dM;
        const float* obs_t = obs + (size_t)t * Bb;
        const float* eps_t = eps + (size_t)t * P * dL;
        const float* u_t   = gum + (size_t)t * P * Nn;
        float* out_t = out + (size_t)t * Bb * dL;

        k1_build_inp<<<P / 4, 256, 0, stream>>>(rl, z, h_t, pe_emb, Xhi, Xlo);
        mfma_gemm<416, 256, 0><<<dim3(128, 4), 256, 0, stream>>>(
            Xhi, Xlo, w_pz1h, w_pz1l, pz_b1, H1hi, H1lo);
        mfma_gemm<256, 256, 0><<<dim3(128, 4), 256, 0, stream>>>(
            H1hi, H1lo, w_pz2h, w_pz2l, pz_b2, H2hi, H2lo);
        mfma_gemm<256, 256, 1><<<dim3(128, 4), 256, 0, stream>>>(
            H2hi, H2lo, w_pz3h, w_pz3l, pz_b3, ZPf, nullptr);
        mfma_gemm<416, 256, 0><<<dim3(128, 4), 256, 0, stream>>>(
            Xhi, Xlo, w_pr1h, w_pr1l, pr_b1, HRhi, HRlo);
        k6_mid<<<P / 4, 256, 0, stream>>>(ZPf, HRhi, HRlo, eps_t, pr_w2, pr_b2,
                                          h_t, z_new, rlog, log_q,
                                          X2hi, X2lo, vthi, vtlo);
        mfma_gemm<384, 256, 0><<<dim3(128, 4), 256, 0, stream>>>(
            X2hi, X2lo, w_oe1h, w_oe1l, oe_b1, E1hi, E1lo);
        mfma_gemm<256, 128, 0><<<dim3(128, 2), 256, 0, stream>>>(
            E1hi, E1lo, w_oe2h, w_oe2l, oe_b2, E2hi, E2lo);
        k9_logw<<<P / 4, 256, 0, stream>>>(E2hi, E2lo, rlog, log_q, oe_w3, oe_b3,
                                           obs_t, los, log_w);
        k10_mean<<<Bb, 256, 0, stream>>>(log_w, z_new, out_t);
        k11_weights<<<P / 4, 256, 0, stream>>>(log_w, u_t, Ahi, Alo, rl);
        k12_mfma<<<dim3(16, 8, 3), 256, 0, stream>>>(Ahi, Alo, vthi, vtlo, z, rl);
    }
}